// Round 3
// baseline (375.834 us; speedup 1.0000x reference)
//
#include <hip/hip_runtime.h>
#include <hip/hip_bf16.h>

typedef __bf16 bf16x8 __attribute__((ext_vector_type(8)));
typedef float  f32x4  __attribute__((ext_vector_type(4)));

#define SIZE_  131072
#define DIM_   128
#define BATCH_ 1024
#define KNN_   16

#define NB 64   // bank rows per block (B-panel)

// ---------------- prep: emb -> bf16 + e_sq ----------------
__global__ __launch_bounds__(256) void prep_emb(const float* __restrict__ emb,
                                                __bf16* __restrict__ emb16,
                                                float* __restrict__ e_sq) {
    int wid  = (blockIdx.x * 256 + threadIdx.x) >> 6;   // row 0..1023
    int lane = threadIdx.x & 63;
    float2 v = *reinterpret_cast<const float2*>(emb + (size_t)wid * DIM_ + lane * 2);
    float s = v.x * v.x + v.y * v.y;
    #pragma unroll
    for (int off = 32; off; off >>= 1) s += __shfl_xor(s, off);
    union { __bf16 h[2]; unsigned int u; } pk;
    pk.h[0] = (__bf16)v.x; pk.h[1] = (__bf16)v.y;
    *reinterpret_cast<unsigned int*>(emb16 + (size_t)wid * DIM_ + lane * 2) = pk.u;
    if (lane == 0) e_sq[wid] = s;
}

// ---------------- fused: B-panel stage + bank copy + b_sq + GEMM + distance ----------------
// One block per 64-row bank panel. Bank read from HBM exactly once.
// A (emb16, 256KB) loaded directly from global (L2-resident) per fragment.
__global__ __launch_bounds__(256, 4) void gemm_fused(const float* __restrict__ bank,
                                                     const __bf16* __restrict__ emb16,
                                                     const float* __restrict__ e_sq,
                                                     float* __restrict__ out_dist,
                                                     float* __restrict__ out_dots,
                                                     float* __restrict__ out_bank) {
    __shared__ __bf16 lB[NB * DIM_];    // 16 KB, XOR-swizzled rows
    __shared__ float  bsq[NB];          // 256 B
    __shared__ float  esq[BATCH_];      // 4 KB
    char* lBc = (char*)lB;

    int n0  = blockIdx.x * NB;
    int tid = threadIdx.x;

    // ---- stage B panel: read f32 bank rows once; emit copy + b_sq + bf16 LDS ----
    #pragma unroll
    for (int i = 0; i < 8; ++i) {
        int p   = i * 256 + tid;          // 0..2047 float4-chunks
        int row = p >> 5;                 // 32 chunks per row
        int c4  = p & 31;
        size_t gb = (size_t)(n0 + row) * DIM_ + c4 * 4;
        f32x4 v = *reinterpret_cast<const f32x4*>(bank + gb);
        __builtin_nontemporal_store(v, reinterpret_cast<f32x4*>(out_bank + gb));
        float s = v.x * v.x + v.y * v.y + v.z * v.z + v.w * v.w;
        #pragma unroll
        for (int off = 16; off; off >>= 1) s += __shfl_xor(s, off);   // reduce within 32-lane row group
        if (c4 == 0) bsq[row] = s;
        union { __bf16 h[4]; unsigned long long u; } pk;
        pk.h[0] = (__bf16)v.x; pk.h[1] = (__bf16)v.y;
        pk.h[2] = (__bf16)v.z; pk.h[3] = (__bf16)v.w;
        int o  = (row << 8) + c4 * 8;                 // byte offset, 256 B/row
        int so = o ^ ((row & 7) << 4);                // bank-conflict swizzle
        *reinterpret_cast<unsigned long long*>(lBc + so) = pk.u;
    }
    // ---- stage e_sq (4 KB) ----
    {
        f32x4 v = *reinterpret_cast<const f32x4*>(e_sq + tid * 4);
        *reinterpret_cast<f32x4*>(esq + tid * 4) = v;
    }
    __syncthreads();

    int wv   = tid >> 6;
    int lane = tid & 63;
    int lr   = lane & 15;
    int lkb  = (lane >> 4) * 8;
    int rgrp = lane >> 4;

    // ---- 4 M-chunks of 256 emb rows each; wave covers 64 rows x 64 cols ----
    for (int mc = 0; mc < 4; ++mc) {
        int mbase = mc * 256 + wv * 64;
        f32x4 acc[4][4] = {};

        #pragma unroll
        for (int ks = 0; ks < 4; ++ks) {
            int kk = ks * 32 + lkb;
            bf16x8 af[4], bf[4];
            #pragma unroll
            for (int mr = 0; mr < 4; ++mr)
                af[mr] = *reinterpret_cast<const bf16x8*>(emb16 + (size_t)(mbase + mr * 16 + lr) * DIM_ + kk);
            #pragma unroll
            for (int nc = 0; nc < 4; ++nc) {
                int row = nc * 16 + lr;
                int o   = (row << 8) + kk * 2;
                bf[nc]  = *reinterpret_cast<const bf16x8*>(lBc + (o ^ ((row & 7) << 4)));
            }
            #pragma unroll
            for (int mr = 0; mr < 4; ++mr)
                #pragma unroll
                for (int nc = 0; nc < 4; ++nc)
                    acc[mr][nc] = __builtin_amdgcn_mfma_f32_16x16x32_bf16(af[mr], bf[nc], acc[mr][nc], 0, 0, 0);
        }

        // ---- fused distance epilogue, nontemporal streaming stores ----
        #pragma unroll
        for (int mr = 0; mr < 4; ++mr) {
            #pragma unroll
            for (int j = 0; j < 4; ++j) {
                int grow = mbase + mr * 16 + rgrp * 4 + j;
                float es = esq[grow];
                size_t rb = (size_t)grow * SIZE_;
                #pragma unroll
                for (int nc = 0; nc < 4; ++nc) {
                    int gcol = n0 + nc * 16 + lr;
                    float d  = acc[mr][nc][j];
                    float arg = es + bsq[nc * 16 + lr] - 2.0f * d;
                    __builtin_nontemporal_store(sqrtf(fmaxf(arg, 0.0f)), out_dist + rb + gcol);
                    __builtin_nontemporal_store(d, out_dots + rb + gcol);
                }
            }
        }
    }
}

// ---------------- scatter rows (last occurrence wins) ----------------
__global__ __launch_bounds__(128) void scatter_rows(const float* __restrict__ dmem,
                                                    const int* __restrict__ upd,
                                                    float* __restrict__ newbank) {
    int i = blockIdx.x;
    int idx = upd[i];
    __shared__ int dup;
    if (threadIdx.x == 0) dup = 0;
    __syncthreads();
    for (int j = i + 1 + threadIdx.x; j < BATCH_; j += 128)
        if (upd[j] == idx) dup = 1;
    __syncthreads();
    if (dup) return;
    newbank[(size_t)idx * DIM_ + threadIdx.x] = dmem[(size_t)i * DIM_ + threadIdx.x];
}

// ---------------- knn dots (one wave per (b,k), exact f32) ----------------
__global__ __launch_bounds__(256) void knn_kernel(const float* __restrict__ bank,
                                                  const float* __restrict__ emb,
                                                  const int* __restrict__ idxs,
                                                  float* __restrict__ knn) {
    int wid  = (blockIdx.x * 256 + threadIdx.x) >> 6;  // 0..16383
    int lane = threadIdx.x & 63;
    int b    = wid >> 4;
    int idx  = idxs[wid];
    float2 br = *reinterpret_cast<const float2*>(bank + (size_t)idx * DIM_ + lane * 2);
    float2 er = *reinterpret_cast<const float2*>(emb + (size_t)b * DIM_ + lane * 2);
    float s = br.x * er.x + br.y * er.y;
    #pragma unroll
    for (int off = 32; off; off >>= 1) s += __shfl_xor(s, off);
    if (lane == 0) knn[wid] = s;
}

extern "C" void kernel_launch(void* const* d_in, const int* in_sizes, int n_in,
                              void* d_out, int out_size, void* d_ws, size_t ws_size,
                              hipStream_t stream) {
    const float* emb  = (const float*)d_in[0];
    const float* dmem = (const float*)d_in[1];
    const float* bank = (const float*)d_in[2];
    const int*   idxs = (const int*)d_in[3];
    const int*   upd  = (const int*)d_in[4];

    float* out       = (float*)d_out;
    float* out_dist  = out;
    float* out_dots  = out + (size_t)BATCH_ * SIZE_;
    float* out_knn   = out + (size_t)2 * BATCH_ * SIZE_;
    float* out_bank  = out_knn + (size_t)BATCH_ * KNN_;

    char*   ws    = (char*)d_ws;
    float*  e_sq  = (float*)ws;                        // 1024 f32 = 4 KB
    __bf16* emb16 = (__bf16*)(ws + 4096);              // 1024*128 bf16 = 256 KB

    prep_emb  <<<BATCH_ / 4, 256, 0, stream>>>(emb, emb16, e_sq);
    gemm_fused<<<SIZE_ / NB, 256, 0, stream>>>(bank, emb16, e_sq, out_dist, out_dots, out_bank);
    scatter_rows<<<BATCH_, 128, 0, stream>>>(dmem, upd, out_bank);
    knn_kernel<<<(BATCH_ * KNN_) / 4, 256, 0, stream>>>(bank, emb, idxs, out_knn);
}